// Round 4
// baseline (494.511 us; speedup 1.0000x reference)
//
#include <hip/hip_runtime.h>
#include <hip/hip_cooperative_groups.h>

#define FEA   128   // floats per atom row (512 B)
#define CHUNK 128   // atoms per wave (64 KB contiguous stream per wave)

typedef float f4 __attribute__((ext_vector_type(4)));

namespace cg = cooperative_groups;

// ---------------------------------------------------------------------------
// Fused cooperative kernel.
// Phase 1: build B[s] = lower_bound(ids, s); zero rows of empty segments and
//          of segments straddling a CHUNK boundary (they get atomicAdd later).
// grid.sync()
// Phase 2: one wave per 128-atom chunk; interior segments -> direct mean
//          write (exclusive owner); straddlers -> pre-divided atomicAdd.
// ---------------------------------------------------------------------------
__global__ __launch_bounds__(256, 8) void segmean_fused_kernel(
    const float* __restrict__ atom_fea,
    const int*   __restrict__ ids,
    int*         __restrict__ B,
    float*       __restrict__ out,
    int n_atoms, int n_seg)
{
    const int tid       = blockIdx.x * 256 + threadIdx.x;
    const int n_threads = gridDim.x * 256;
    const int n_chunks  = (n_atoms + CHUNK - 1) / CHUNK;

    // ---------------- Phase 1a: bounds + empty-row zeroing ----------------
    for (int t = tid; t * 4 < n_atoms; t += n_threads) {
        const int i0 = t * 4;
        int prev = (i0 == 0) ? -1 : ids[i0 - 1];
        #pragma unroll
        for (int j = 0; j < 4; ++j) {
            const int i = i0 + j;
            if (i >= n_atoms) break;
            const int cur = ids[i];
            if (cur != prev) {
                for (int s = prev + 1; s <= cur; ++s) B[s] = i;
                for (int s = prev + 1; s < cur; ++s) {        // empty segments
                    f4* row = (f4*)(out + (size_t)s * FEA);
                    const f4 z = {0.f, 0.f, 0.f, 0.f};
                    for (int q = 0; q < FEA / 4; ++q) row[q] = z;
                }
                prev = cur;
            }
        }
        if (i0 + 4 >= n_atoms) {                               // covers last atom
            for (int s = prev + 1; s <= n_seg; ++s) B[s] = n_atoms;
            for (int s = prev + 1; s < n_seg; ++s) {
                f4* row = (f4*)(out + (size_t)s * FEA);
                const f4 z = {0.f, 0.f, 0.f, 0.f};
                for (int q = 0; q < FEA / 4; ++q) row[q] = z;
            }
        }
    }

    // ---------------- Phase 1b: zero straddler rows (32 lanes/boundary) ----
    for (int t = tid; t < (n_chunks - 1) * 32; t += n_threads) {
        const int b = t >> 5;
        const int g = t & 31;
        const int p = (b + 1) * CHUNK;
        if (p < n_atoms && ids[p - 1] == ids[p]) {
            const f4 z = {0.f, 0.f, 0.f, 0.f};
            ((f4*)(out + (size_t)ids[p] * FEA))[g] = z;
        }
    }

    __threadfence();
    cg::this_grid().sync();

    // ---------------- Phase 2: stream chunks ------------------------------
    const int lane   = threadIdx.x & 63;
    const int a_sub  = lane >> 5;
    const int g      = lane & 31;
    const int wave0  = tid >> 6;
    const int nwaves = n_threads >> 6;

    for (int wid = wave0; wid < n_chunks; wid += nwaves) {
        const int c0 = wid * CHUNK;
        const int c1 = min(c0 + CHUNK, n_atoms);

        int s   = ids[c0];
        int pos = c0;

        while (pos < c1) {
            const int segS = B[s];
            const int segE = B[s + 1];
            const int e    = min(segE, c1);
            const int m    = e - pos;

            const f4* base = (const f4*)atom_fea + (size_t)pos * (FEA / 4) + g;

            f4 a0 = {0.f, 0.f, 0.f, 0.f};
            f4 a1 = {0.f, 0.f, 0.f, 0.f};
            f4 a2 = {0.f, 0.f, 0.f, 0.f};
            f4 a3 = {0.f, 0.f, 0.f, 0.f};

            int k = a_sub;
            for (; k + 6 < m; k += 8) {        // 4 loads (4 KB/wave-iter) in flight
                f4 v0 = base[(size_t)k       * 32];
                f4 v1 = base[(size_t)(k + 2) * 32];
                f4 v2 = base[(size_t)(k + 4) * 32];
                f4 v3 = base[(size_t)(k + 6) * 32];
                a0 += v0; a1 += v1; a2 += v2; a3 += v3;
            }
            for (; k < m; k += 2)
                a0 += base[(size_t)k * 32];

            a0 += a1 + a2 + a3;

            a0[0] += __shfl_xor(a0[0], 32, 64);
            a0[1] += __shfl_xor(a0[1], 32, 64);
            a0[2] += __shfl_xor(a0[2], 32, 64);
            a0[3] += __shfl_xor(a0[3], 32, 64);

            const int   n_total = segE - segS;
            const float invn    = 1.0f / (float)((n_total > 0) ? n_total : 1);

            if (segS >= c0 && segE <= c1) {
                if (a_sub == 0) {
                    f4 r = a0 * invn;
                    ((f4*)(out + (size_t)s * FEA))[g] = r;
                }
            } else {
                if (a_sub == 0) {
                    float* dst = out + (size_t)s * FEA + g * 4;
                    atomicAdd(dst + 0, a0[0] * invn);
                    atomicAdd(dst + 1, a0[1] * invn);
                    atomicAdd(dst + 2, a0[2] * invn);
                    atomicAdd(dst + 3, a0[3] * invn);
                }
            }
            pos = e;
            ++s;
        }
    }
}

// ---------------------------------------------------------------------------
// Fallback path (cooperative launch refused): R3's two-kernel structure.
// ---------------------------------------------------------------------------
__global__ __launch_bounds__(256) void prologue_kernel(
    const int* __restrict__ ids, int* __restrict__ B, float* __restrict__ out,
    int n_atoms, int n_seg, int b_blocks, int n_chunks)
{
    if ((int)blockIdx.x < b_blocks) {
        const int t  = blockIdx.x * 256 + threadIdx.x;
        const int i0 = t * 4;
        if (i0 >= n_atoms) return;
        int prev = (i0 == 0) ? -1 : ids[i0 - 1];
        #pragma unroll
        for (int j = 0; j < 4; ++j) {
            const int i = i0 + j;
            if (i >= n_atoms) break;
            const int cur = ids[i];
            if (cur != prev) {
                for (int s = prev + 1; s <= cur; ++s) B[s] = i;
                for (int s = prev + 1; s < cur; ++s) {
                    f4* row = (f4*)(out + (size_t)s * FEA);
                    const f4 z = {0.f, 0.f, 0.f, 0.f};
                    for (int q = 0; q < FEA / 4; ++q) row[q] = z;
                }
                prev = cur;
            }
        }
        if (i0 + 4 >= n_atoms) {
            for (int s = prev + 1; s <= n_seg; ++s) B[s] = n_atoms;
            for (int s = prev + 1; s < n_seg; ++s) {
                f4* row = (f4*)(out + (size_t)s * FEA);
                const f4 z = {0.f, 0.f, 0.f, 0.f};
                for (int q = 0; q < FEA / 4; ++q) row[q] = z;
            }
        }
    } else {
        const int t = ((int)blockIdx.x - b_blocks) * 256 + threadIdx.x;
        const int b = t >> 5;
        const int g = t & 31;
        const int p = (b + 1) * CHUNK;
        if (b >= n_chunks - 1 || p >= n_atoms) return;
        if (ids[p - 1] == ids[p]) {
            const f4 z = {0.f, 0.f, 0.f, 0.f};
            ((f4*)(out + (size_t)ids[p] * FEA))[g] = z;
        }
    }
}

__global__ __launch_bounds__(256) void segmean_chunk_kernel(
    const float* __restrict__ atom_fea,
    const int*   __restrict__ ids,
    const int*   __restrict__ B,
    float*       __restrict__ out,
    int n_atoms)
{
    const int wid   = (blockIdx.x * 256 + threadIdx.x) >> 6;
    const int lane  = threadIdx.x & 63;
    const int c0    = wid * CHUNK;
    if (c0 >= n_atoms) return;
    const int c1    = min(c0 + CHUNK, n_atoms);
    const int a_sub = lane >> 5;
    const int g     = lane & 31;

    int s   = ids[c0];
    int pos = c0;

    while (pos < c1) {
        const int segS = B[s];
        const int segE = B[s + 1];
        const int e    = min(segE, c1);
        const int m    = e - pos;

        const f4* base = (const f4*)atom_fea + (size_t)pos * (FEA / 4) + g;

        f4 a0 = {0.f, 0.f, 0.f, 0.f};
        f4 a1 = {0.f, 0.f, 0.f, 0.f};
        f4 a2 = {0.f, 0.f, 0.f, 0.f};
        f4 a3 = {0.f, 0.f, 0.f, 0.f};

        int k = a_sub;
        for (; k + 6 < m; k += 8) {
            f4 v0 = base[(size_t)k       * 32];
            f4 v1 = base[(size_t)(k + 2) * 32];
            f4 v2 = base[(size_t)(k + 4) * 32];
            f4 v3 = base[(size_t)(k + 6) * 32];
            a0 += v0; a1 += v1; a2 += v2; a3 += v3;
        }
        for (; k < m; k += 2)
            a0 += base[(size_t)k * 32];

        a0 += a1 + a2 + a3;

        a0[0] += __shfl_xor(a0[0], 32, 64);
        a0[1] += __shfl_xor(a0[1], 32, 64);
        a0[2] += __shfl_xor(a0[2], 32, 64);
        a0[3] += __shfl_xor(a0[3], 32, 64);

        const int   n_total = segE - segS;
        const float invn    = 1.0f / (float)((n_total > 0) ? n_total : 1);

        if (segS >= c0 && segE <= c1) {
            if (a_sub == 0) {
                f4 r = a0 * invn;
                ((f4*)(out + (size_t)s * FEA))[g] = r;
            }
        } else {
            if (a_sub == 0) {
                float* dst = out + (size_t)s * FEA + g * 4;
                atomicAdd(dst + 0, a0[0] * invn);
                atomicAdd(dst + 1, a0[1] * invn);
                atomicAdd(dst + 2, a0[2] * invn);
                atomicAdd(dst + 3, a0[3] * invn);
            }
        }
        pos = e;
        ++s;
    }
}

extern "C" void kernel_launch(void* const* d_in, const int* in_sizes, int n_in,
                              void* d_out, int out_size, void* d_ws, size_t ws_size,
                              hipStream_t stream) {
    const float* atom_fea = (const float*)d_in[0];
    const int*   ids      = (const int*)d_in[1];
    float*       out      = (float*)d_out;

    int n_atoms = in_sizes[1];
    int n_seg   = out_size / FEA;

    const size_t bounds_bytes = (size_t)(n_seg + 1) * sizeof(int);
    const int    n_chunks     = (n_atoms + CHUNK - 1) / CHUNK;

    if (ws_size >= bounds_bytes) {
        int* B = (int*)d_ws;

        // Cooperative fused launch: 2048 blocks x 256 threads = exactly the
        // co-resident capacity at 8 blocks/CU (launch_bounds pins VGPR<=64).
        void* args[] = {(void*)&atom_fea, (void*)&ids, (void*)&B, (void*)&out,
                        (void*)&n_atoms, (void*)&n_seg};
        hipError_t err = hipLaunchCooperativeKernel(
            (const void*)segmean_fused_kernel, dim3(2048), dim3(256),
            args, 0, stream);

        if (err != hipSuccess) {
            // Fallback: two-kernel path (identical semantics).
            const int b_blocks = (((n_atoms + 3) / 4) + 255) / 256;
            const int z_thr    = (n_chunks > 1) ? (n_chunks - 1) * 32 : 0;
            const int z_blocks = (z_thr + 255) / 256;
            prologue_kernel<<<b_blocks + z_blocks, 256, 0, stream>>>(
                ids, B, out, n_atoms, n_seg, b_blocks, n_chunks);
            const int m_blocks = (n_chunks + 3) / 4;
            segmean_chunk_kernel<<<m_blocks, 256, 0, stream>>>(
                atom_fea, ids, B, out, n_atoms);
        }
    } else {
        // ws too small (never expected): two-kernel path needs B, so fall back
        // to chunk kernel with B built in the out buffer? Not possible safely;
        // use prologue-free path: one wave per segment with binary search.
        // (Kept minimal: reuse chunk kernels is impossible without B, so this
        // path simply should not occur given ws_size >> 64 KB.)
        const int b_blocks = (((n_atoms + 3) / 4) + 255) / 256;
        const int z_thr    = (n_chunks > 1) ? (n_chunks - 1) * 32 : 0;
        const int z_blocks = (z_thr + 255) / 256;
        int* B = (int*)d_ws;  // best effort
        prologue_kernel<<<b_blocks + z_blocks, 256, 0, stream>>>(
            ids, B, out, n_atoms, n_seg, b_blocks, n_chunks);
        const int m_blocks = (n_chunks + 3) / 4;
        segmean_chunk_kernel<<<m_blocks, 256, 0, stream>>>(
            atom_fea, ids, B, out, n_atoms);
    }
}

// Round 5
// 311.649 us; speedup vs baseline: 1.5868x; 1.5868x over previous
//
#include <hip/hip_runtime.h>
#include <hip/hip_cooperative_groups.h>

#define FEA   128   // floats per atom row (512 B)
#define CHUNK 128   // atoms per wave-iteration chunk (64 KB contiguous)

typedef float f4 __attribute__((ext_vector_type(4)));

namespace cg = cooperative_groups;

// ---------------------------------------------------------------------------
// Fused cooperative kernel. Grid = 1024 blocks x 256 thr (4 blocks/CU
// co-resident, __launch_bounds__(256,4) -> VGPR cap 128: no spill, full
// 4-deep load pipeline).
// Phase 1: B[s] = lower_bound(ids, s); zero empty-segment rows and rows of
//          segments straddling a CHUNK boundary.
// grid.sync()
// Phase 2: grid-stride over 128-atom chunks (2 per wave, uniform work);
//          interior segments -> direct mean write; straddlers -> pre-divided
//          atomicAdd into the zeroed row.
// ---------------------------------------------------------------------------
__global__ __launch_bounds__(256, 4) void segmean_fused_kernel(
    const float* __restrict__ atom_fea,
    const int*   __restrict__ ids,
    int*         __restrict__ B,
    float*       __restrict__ out,
    int n_atoms, int n_seg)
{
    const int tid       = blockIdx.x * 256 + threadIdx.x;
    const int n_threads = gridDim.x * 256;
    const int n_chunks  = (n_atoms + CHUNK - 1) / CHUNK;

    // ---------------- Phase 1a: bounds + empty-row zeroing ----------------
    for (int t = tid; t * 4 < n_atoms; t += n_threads) {
        const int i0 = t * 4;
        int prev = (i0 == 0) ? -1 : ids[i0 - 1];
        if (i0 + 3 < n_atoms) {
            const int4 v = *(const int4*)(ids + i0);
            const int cur[4] = {v.x, v.y, v.z, v.w};
            #pragma unroll
            for (int j = 0; j < 4; ++j) {
                if (cur[j] != prev) {
                    for (int s = prev + 1; s <= cur[j]; ++s) B[s] = i0 + j;
                    for (int s = prev + 1; s < cur[j]; ++s) {   // empty segments
                        f4* row = (f4*)(out + (size_t)s * FEA);
                        const f4 z = {0.f, 0.f, 0.f, 0.f};
                        for (int q = 0; q < FEA / 4; ++q) row[q] = z;
                    }
                    prev = cur[j];
                }
            }
            if (i0 + 4 == n_atoms) {
                for (int s = prev + 1; s <= n_seg; ++s) B[s] = n_atoms;
                for (int s = prev + 1; s < n_seg; ++s) {
                    f4* row = (f4*)(out + (size_t)s * FEA);
                    const f4 z = {0.f, 0.f, 0.f, 0.f};
                    for (int q = 0; q < FEA / 4; ++q) row[q] = z;
                }
            }
        } else {
            for (int j = 0; j < 4 && i0 + j < n_atoms; ++j) {
                const int c = ids[i0 + j];
                if (c != prev) {
                    for (int s = prev + 1; s <= c; ++s) B[s] = i0 + j;
                    for (int s = prev + 1; s < c; ++s) {
                        f4* row = (f4*)(out + (size_t)s * FEA);
                        const f4 z = {0.f, 0.f, 0.f, 0.f};
                        for (int q = 0; q < FEA / 4; ++q) row[q] = z;
                    }
                    prev = c;
                }
            }
            for (int s = prev + 1; s <= n_seg; ++s) B[s] = n_atoms;
            for (int s = prev + 1; s < n_seg; ++s) {
                f4* row = (f4*)(out + (size_t)s * FEA);
                const f4 z = {0.f, 0.f, 0.f, 0.f};
                for (int q = 0; q < FEA / 4; ++q) row[q] = z;
            }
        }
    }

    // ---------------- Phase 1b: zero straddler rows (32 lanes/boundary) ----
    for (int t = tid; t < (n_chunks - 1) * 32; t += n_threads) {
        const int b = t >> 5;
        const int g = t & 31;
        const int p = (b + 1) * CHUNK;
        if (p < n_atoms && ids[p - 1] == ids[p]) {
            const f4 z = {0.f, 0.f, 0.f, 0.f};
            ((f4*)(out + (size_t)ids[p] * FEA))[g] = z;
        }
    }

    __threadfence();
    cg::this_grid().sync();

    // ---------------- Phase 2: stream chunks (grid-stride, uniform) --------
    const int lane   = threadIdx.x & 63;
    const int a_sub  = lane >> 5;
    const int g      = lane & 31;
    const int wave0  = tid >> 6;
    const int nwaves = n_threads >> 6;

    for (int wid = wave0; wid < n_chunks; wid += nwaves) {
        const int c0 = wid * CHUNK;
        const int c1 = min(c0 + CHUNK, n_atoms);

        int s   = ids[c0];
        int pos = c0;

        while (pos < c1) {
            const int segS = B[s];
            const int segE = B[s + 1];
            const int e    = min(segE, c1);
            const int m    = e - pos;

            const f4* base = (const f4*)atom_fea + (size_t)pos * (FEA / 4) + g;

            f4 a0 = {0.f, 0.f, 0.f, 0.f};
            f4 a1 = {0.f, 0.f, 0.f, 0.f};
            f4 a2 = {0.f, 0.f, 0.f, 0.f};
            f4 a3 = {0.f, 0.f, 0.f, 0.f};

            int k = a_sub;
            for (; k + 6 < m; k += 8) {        // 4 loads (4 KB/wave-iter) in flight
                f4 v0 = base[(size_t)k       * 32];
                f4 v1 = base[(size_t)(k + 2) * 32];
                f4 v2 = base[(size_t)(k + 4) * 32];
                f4 v3 = base[(size_t)(k + 6) * 32];
                a0 += v0; a1 += v1; a2 += v2; a3 += v3;
            }
            for (; k < m; k += 2)
                a0 += base[(size_t)k * 32];

            a0 += a1 + a2 + a3;

            a0[0] += __shfl_xor(a0[0], 32, 64);
            a0[1] += __shfl_xor(a0[1], 32, 64);
            a0[2] += __shfl_xor(a0[2], 32, 64);
            a0[3] += __shfl_xor(a0[3], 32, 64);

            const int   n_total = segE - segS;
            const float invn    = 1.0f / (float)((n_total > 0) ? n_total : 1);

            if (segS >= c0 && segE <= c1) {
                if (a_sub == 0) {
                    f4 r = a0 * invn;
                    ((f4*)(out + (size_t)s * FEA))[g] = r;
                }
            } else {
                if (a_sub == 0) {
                    float* dst = out + (size_t)s * FEA + g * 4;
                    atomicAdd(dst + 0, a0[0] * invn);
                    atomicAdd(dst + 1, a0[1] * invn);
                    atomicAdd(dst + 2, a0[2] * invn);
                    atomicAdd(dst + 3, a0[3] * invn);
                }
            }
            pos = e;
            ++s;
        }
    }
}

// ---------------------------------------------------------------------------
// Fallback path (cooperative launch refused): R3's two-kernel structure.
// ---------------------------------------------------------------------------
__global__ __launch_bounds__(256) void prologue_kernel(
    const int* __restrict__ ids, int* __restrict__ B, float* __restrict__ out,
    int n_atoms, int n_seg, int b_blocks, int n_chunks)
{
    if ((int)blockIdx.x < b_blocks) {
        const int t  = blockIdx.x * 256 + threadIdx.x;
        const int i0 = t * 4;
        if (i0 >= n_atoms) return;
        int prev = (i0 == 0) ? -1 : ids[i0 - 1];
        #pragma unroll
        for (int j = 0; j < 4; ++j) {
            const int i = i0 + j;
            if (i >= n_atoms) break;
            const int cur = ids[i];
            if (cur != prev) {
                for (int s = prev + 1; s <= cur; ++s) B[s] = i;
                for (int s = prev + 1; s < cur; ++s) {
                    f4* row = (f4*)(out + (size_t)s * FEA);
                    const f4 z = {0.f, 0.f, 0.f, 0.f};
                    for (int q = 0; q < FEA / 4; ++q) row[q] = z;
                }
                prev = cur;
            }
        }
        if (i0 + 4 >= n_atoms) {
            for (int s = prev + 1; s <= n_seg; ++s) B[s] = n_atoms;
            for (int s = prev + 1; s < n_seg; ++s) {
                f4* row = (f4*)(out + (size_t)s * FEA);
                const f4 z = {0.f, 0.f, 0.f, 0.f};
                for (int q = 0; q < FEA / 4; ++q) row[q] = z;
            }
        }
    } else {
        const int t = ((int)blockIdx.x - b_blocks) * 256 + threadIdx.x;
        const int b = t >> 5;
        const int g = t & 31;
        const int p = (b + 1) * CHUNK;
        if (b >= n_chunks - 1 || p >= n_atoms) return;
        if (ids[p - 1] == ids[p]) {
            const f4 z = {0.f, 0.f, 0.f, 0.f};
            ((f4*)(out + (size_t)ids[p] * FEA))[g] = z;
        }
    }
}

__global__ __launch_bounds__(256) void segmean_chunk_kernel(
    const float* __restrict__ atom_fea,
    const int*   __restrict__ ids,
    const int*   __restrict__ B,
    float*       __restrict__ out,
    int n_atoms)
{
    const int wid   = (blockIdx.x * 256 + threadIdx.x) >> 6;
    const int lane  = threadIdx.x & 63;
    const int c0    = wid * CHUNK;
    if (c0 >= n_atoms) return;
    const int c1    = min(c0 + CHUNK, n_atoms);
    const int a_sub = lane >> 5;
    const int g     = lane & 31;

    int s   = ids[c0];
    int pos = c0;

    while (pos < c1) {
        const int segS = B[s];
        const int segE = B[s + 1];
        const int e    = min(segE, c1);
        const int m    = e - pos;

        const f4* base = (const f4*)atom_fea + (size_t)pos * (FEA / 4) + g;

        f4 a0 = {0.f, 0.f, 0.f, 0.f};
        f4 a1 = {0.f, 0.f, 0.f, 0.f};
        f4 a2 = {0.f, 0.f, 0.f, 0.f};
        f4 a3 = {0.f, 0.f, 0.f, 0.f};

        int k = a_sub;
        for (; k + 6 < m; k += 8) {
            f4 v0 = base[(size_t)k       * 32];
            f4 v1 = base[(size_t)(k + 2) * 32];
            f4 v2 = base[(size_t)(k + 4) * 32];
            f4 v3 = base[(size_t)(k + 6) * 32];
            a0 += v0; a1 += v1; a2 += v2; a3 += v3;
        }
        for (; k < m; k += 2)
            a0 += base[(size_t)k * 32];

        a0 += a1 + a2 + a3;

        a0[0] += __shfl_xor(a0[0], 32, 64);
        a0[1] += __shfl_xor(a0[1], 32, 64);
        a0[2] += __shfl_xor(a0[2], 32, 64);
        a0[3] += __shfl_xor(a0[3], 32, 64);

        const int   n_total = segE - segS;
        const float invn    = 1.0f / (float)((n_total > 0) ? n_total : 1);

        if (segS >= c0 && segE <= c1) {
            if (a_sub == 0) {
                f4 r = a0 * invn;
                ((f4*)(out + (size_t)s * FEA))[g] = r;
            }
        } else {
            if (a_sub == 0) {
                float* dst = out + (size_t)s * FEA + g * 4;
                atomicAdd(dst + 0, a0[0] * invn);
                atomicAdd(dst + 1, a0[1] * invn);
                atomicAdd(dst + 2, a0[2] * invn);
                atomicAdd(dst + 3, a0[3] * invn);
            }
        }
        pos = e;
        ++s;
    }
}

extern "C" void kernel_launch(void* const* d_in, const int* in_sizes, int n_in,
                              void* d_out, int out_size, void* d_ws, size_t ws_size,
                              hipStream_t stream) {
    const float* atom_fea = (const float*)d_in[0];
    const int*   ids      = (const int*)d_in[1];
    float*       out      = (float*)d_out;

    int n_atoms = in_sizes[1];
    int n_seg   = out_size / FEA;

    const size_t bounds_bytes = (size_t)(n_seg + 1) * sizeof(int);
    const int    n_chunks     = (n_atoms + CHUNK - 1) / CHUNK;

    bool launched = false;
    if (ws_size >= bounds_bytes) {
        int* B = (int*)d_ws;
        // 1024 blocks = 4 blocks/CU co-resident (guaranteed by
        // __launch_bounds__(256,4) -> VGPR <= 128, no spill).
        void* args[] = {(void*)&atom_fea, (void*)&ids, (void*)&B, (void*)&out,
                        (void*)&n_atoms, (void*)&n_seg};
        hipError_t err = hipLaunchCooperativeKernel(
            (const void*)segmean_fused_kernel, dim3(1024), dim3(256),
            args, 0, stream);
        launched = (err == hipSuccess);
    }

    if (!launched) {
        // Two-kernel fallback (identical semantics, proven 109 us).
        int* B = (int*)d_ws;
        const int b_blocks = (((n_atoms + 3) / 4) + 255) / 256;
        const int z_thr    = (n_chunks > 1) ? (n_chunks - 1) * 32 : 0;
        const int z_blocks = (z_thr + 255) / 256;
        prologue_kernel<<<b_blocks + z_blocks, 256, 0, stream>>>(
            ids, B, out, n_atoms, n_seg, b_blocks, n_chunks);
        const int m_blocks = (n_chunks + 3) / 4;
        segmean_chunk_kernel<<<m_blocks, 256, 0, stream>>>(
            atom_fea, ids, B, out, n_atoms);
    }
}

// Round 6
// 118.481 us; speedup vs baseline: 4.1737x; 2.6304x over previous
//
#include <hip/hip_runtime.h>

#define FEA   128   // floats per atom row (512 B)
#define CHUNK 256   // atoms per wave (128 KB contiguous stream per wave)

typedef float f4 __attribute__((ext_vector_type(4)));

// ---------------------------------------------------------------------------
// Prologue (one launch, two thread roles by blockIdx):
//  role A: build B[s] = lower_bound(ids, s), s in [0, n_seg]; zero rows of
//          empty segments.
//  role B: for each chunk boundary p = k*CHUNK, if ids[p-1]==ids[p] the
//          segment straddles the boundary -> zero its row (atomicAdd target).
// ---------------------------------------------------------------------------
__global__ __launch_bounds__(256) void prologue_kernel(
    const int* __restrict__ ids, int* __restrict__ B, float* __restrict__ out,
    int n_atoms, int n_seg, int b_blocks, int n_chunks)
{
    if ((int)blockIdx.x < b_blocks) {
        const int t  = blockIdx.x * 256 + threadIdx.x;
        const int i0 = t * 4;
        if (i0 >= n_atoms) return;
        int prev = (i0 == 0) ? -1 : ids[i0 - 1];
        #pragma unroll
        for (int j = 0; j < 4; ++j) {
            const int i = i0 + j;
            if (i >= n_atoms) break;
            const int cur = ids[i];
            if (cur != prev) {
                for (int s = prev + 1; s <= cur; ++s) B[s] = i;
                for (int s = prev + 1; s < cur; ++s) {        // empty segments
                    f4* row = (f4*)(out + (size_t)s * FEA);
                    const f4 z = {0.f, 0.f, 0.f, 0.f};
                    for (int q = 0; q < FEA / 4; ++q) row[q] = z;
                }
                prev = cur;
            }
        }
        if (i0 + 4 >= n_atoms) {
            for (int s = prev + 1; s <= n_seg; ++s) B[s] = n_atoms;
            for (int s = prev + 1; s < n_seg; ++s) {          // trailing empties
                f4* row = (f4*)(out + (size_t)s * FEA);
                const f4 z = {0.f, 0.f, 0.f, 0.f};
                for (int q = 0; q < FEA / 4; ++q) row[q] = z;
            }
        }
    } else {
        const int t = ((int)blockIdx.x - b_blocks) * 256 + threadIdx.x;
        const int b = t >> 5;          // boundary index
        const int g = t & 31;
        const int p = (b + 1) * CHUNK;
        if (b >= n_chunks - 1 || p >= n_atoms) return;
        if (ids[p - 1] == ids[p]) {
            const f4 z = {0.f, 0.f, 0.f, 0.f};
            ((f4*)(out + (size_t)ids[p] * FEA))[g] = z;
        }
    }
}

// ---------------------------------------------------------------------------
// Main: one wave per fixed 256-atom chunk (4096 uniform waves = 16 waves/CU,
// one-shot residency). Walk segments overlapping the chunk via B[]; interior
// segments -> direct mean write (exclusive owner); straddlers -> pre-divided
// atomicAdd into the zeroed row. Lane layout: a_sub in {0,1} picks which of
// 2 concurrent atoms, g in [0,32) picks the float4. 8-deep load pipeline
// (8 KB per wave-iteration in flight).
// ---------------------------------------------------------------------------
__global__ void segmean_chunk_kernel(
    const float* __restrict__ atom_fea,
    const int*   __restrict__ ids,
    const int*   __restrict__ B,
    float*       __restrict__ out,
    int n_atoms)
{
    const int wid   = (blockIdx.x * 256 + threadIdx.x) >> 6;
    const int lane  = threadIdx.x & 63;
    const int c0    = wid * CHUNK;
    if (c0 >= n_atoms) return;
    const int c1    = min(c0 + CHUNK, n_atoms);
    const int a_sub = lane >> 5;
    const int g     = lane & 31;

    int s   = ids[c0];
    int pos = c0;

    while (pos < c1) {
        const int segS = B[s];
        const int segE = B[s + 1];
        const int e    = min(segE, c1);
        const int m    = e - pos;            // atoms of segment s in this chunk

        const f4* base = (const f4*)atom_fea + (size_t)pos * (FEA / 4) + g;

        f4 a0 = {0.f, 0.f, 0.f, 0.f};
        f4 a1 = {0.f, 0.f, 0.f, 0.f};
        f4 a2 = {0.f, 0.f, 0.f, 0.f};
        f4 a3 = {0.f, 0.f, 0.f, 0.f};

        int k = a_sub;
        // 8 loads (8 KB/wave-iter) in flight
        for (; k + 14 < m; k += 16) {
            f4 v0 = base[(size_t)(k     ) * 32];
            f4 v1 = base[(size_t)(k +  2) * 32];
            f4 v2 = base[(size_t)(k +  4) * 32];
            f4 v3 = base[(size_t)(k +  6) * 32];
            f4 v4 = base[(size_t)(k +  8) * 32];
            f4 v5 = base[(size_t)(k + 10) * 32];
            f4 v6 = base[(size_t)(k + 12) * 32];
            f4 v7 = base[(size_t)(k + 14) * 32];
            a0 += v0; a1 += v1; a2 += v2; a3 += v3;
            a0 += v4; a1 += v5; a2 += v6; a3 += v7;
        }
        for (; k + 6 < m; k += 8) {
            f4 v0 = base[(size_t)(k    ) * 32];
            f4 v1 = base[(size_t)(k + 2) * 32];
            f4 v2 = base[(size_t)(k + 4) * 32];
            f4 v3 = base[(size_t)(k + 6) * 32];
            a0 += v0; a1 += v1; a2 += v2; a3 += v3;
        }
        for (; k < m; k += 2)
            a0 += base[(size_t)k * 32];

        a0 += a1 + a2 + a3;

        a0[0] += __shfl_xor(a0[0], 32, 64);
        a0[1] += __shfl_xor(a0[1], 32, 64);
        a0[2] += __shfl_xor(a0[2], 32, 64);
        a0[3] += __shfl_xor(a0[3], 32, 64);

        const int   n_total = segE - segS;
        const float invn    = 1.0f / (float)((n_total > 0) ? n_total : 1);

        if (segS >= c0 && segE <= c1) {
            if (a_sub == 0) {
                f4 r = a0 * invn;
                ((f4*)(out + (size_t)s * FEA))[g] = r;
            }
        } else {
            if (a_sub == 0) {
                float* dst = out + (size_t)s * FEA + g * 4;
                atomicAdd(dst + 0, a0[0] * invn);
                atomicAdd(dst + 1, a0[1] * invn);
                atomicAdd(dst + 2, a0[2] * invn);
                atomicAdd(dst + 3, a0[3] * invn);
            }
        }
        pos = e;
        ++s;
    }
}

// ---------------------------------------------------------------------------
// Fallback (ws too small): self-contained binary-search wave-per-segment.
// ---------------------------------------------------------------------------
__global__ __launch_bounds__(256) void segmean_bsearch_kernel(
    const float* __restrict__ atom_fea,
    const int*   __restrict__ ids,
    float*       __restrict__ out,
    int n_atoms, int n_seg)
{
    const int wave = threadIdx.x >> 6;
    const int lane = threadIdx.x & 63;
    const int seg  = blockIdx.x * 4 + wave;
    if (seg >= n_seg) return;

    int lo0 = 0, hi0 = n_atoms, lo1 = 0, hi1 = n_atoms;
    while ((lo0 < hi0) | (lo1 < hi1)) {
        if (lo0 < hi0) { int m = (lo0 + hi0) >> 1; if (ids[m] < seg)     lo0 = m + 1; else hi0 = m; }
        if (lo1 < hi1) { int m = (lo1 + hi1) >> 1; if (ids[m] < seg + 1) lo1 = m + 1; else hi1 = m; }
    }
    const int start = lo0;
    const int n     = lo1 - lo0;

    const int a_sub = lane >> 5;
    const int g     = lane & 31;
    const f4* base  = (const f4*)atom_fea + (size_t)start * (FEA / 4) + g;

    f4 a0 = {0.f, 0.f, 0.f, 0.f};
    for (int k = a_sub; k < n; k += 2)
        a0 += base[(size_t)k * 32];

    a0[0] += __shfl_xor(a0[0], 32, 64);
    a0[1] += __shfl_xor(a0[1], 32, 64);
    a0[2] += __shfl_xor(a0[2], 32, 64);
    a0[3] += __shfl_xor(a0[3], 32, 64);

    const float invn = 1.0f / (float)((n > 0) ? n : 1);
    if (a_sub == 0) {
        f4 r = a0 * invn;
        ((f4*)(out + (size_t)seg * FEA))[g] = r;
    }
}

extern "C" void kernel_launch(void* const* d_in, const int* in_sizes, int n_in,
                              void* d_out, int out_size, void* d_ws, size_t ws_size,
                              hipStream_t stream) {
    const float* atom_fea = (const float*)d_in[0];
    const int*   ids      = (const int*)d_in[1];
    float*       out      = (float*)d_out;

    const int n_atoms = in_sizes[1];
    const int n_seg   = out_size / FEA;

    const size_t bounds_bytes = (size_t)(n_seg + 1) * sizeof(int);
    const int    n_chunks     = (n_atoms + CHUNK - 1) / CHUNK;

    if (ws_size >= bounds_bytes) {
        int* B = (int*)d_ws;

        const int b_blocks = (((n_atoms + 3) / 4) + 255) / 256;
        const int z_thr    = (n_chunks > 1) ? (n_chunks - 1) * 32 : 0;
        const int z_blocks = (z_thr + 255) / 256;

        prologue_kernel<<<b_blocks + z_blocks, 256, 0, stream>>>(
            ids, B, out, n_atoms, n_seg, b_blocks, n_chunks);

        const int m_blocks = (n_chunks + 3) / 4;   // 4 waves (chunks) per block
        segmean_chunk_kernel<<<m_blocks, 256, 0, stream>>>(
            atom_fea, ids, B, out, n_atoms);
    } else {
        const int seg_blocks = (n_seg + 3) / 4;
        segmean_bsearch_kernel<<<seg_blocks, 256, 0, stream>>>(
            atom_fea, ids, out, n_atoms, n_seg);
    }
}

// Round 7
// 117.857 us; speedup vs baseline: 4.1959x; 1.0053x over previous
//
#include <hip/hip_runtime.h>

#define FEA   128   // floats per atom row (512 B)
#define CHUNK 128   // atom-start window per wave (8192 waves = full residency)

typedef float f4 __attribute__((ext_vector_type(4)));

// ---------------------------------------------------------------------------
// Prologue: build B[s] = lower_bound(ids, s), s in [0, n_seg]. Pure bounds;
// no output writes (empty segments are handled by the main kernel's owners).
// ---------------------------------------------------------------------------
__global__ __launch_bounds__(256) void bounds_kernel(
    const int* __restrict__ ids, int* __restrict__ B, int n_atoms, int n_seg)
{
    const int t  = blockIdx.x * 256 + threadIdx.x;
    const int i0 = t * 4;
    if (i0 >= n_atoms) return;

    int prev = (i0 == 0) ? -1 : ids[i0 - 1];

    if (i0 + 3 < n_atoms) {
        const int4 v = *(const int4*)(ids + i0);
        const int cur[4] = {v.x, v.y, v.z, v.w};
        #pragma unroll
        for (int j = 0; j < 4; ++j) {
            if (cur[j] != prev) {
                for (int s = prev + 1; s <= cur[j]; ++s) B[s] = i0 + j;
                prev = cur[j];
            }
        }
        if (i0 + 4 == n_atoms)
            for (int s = prev + 1; s <= n_seg; ++s) B[s] = n_atoms;
    } else {
        for (int j = 0; j < 4 && i0 + j < n_atoms; ++j) {
            const int c = ids[i0 + j];
            if (c != prev) {
                for (int s = prev + 1; s <= c; ++s) B[s] = i0 + j;
                prev = c;
            }
        }
        for (int s = prev + 1; s <= n_seg; ++s) B[s] = n_atoms;
    }
}

// ---------------------------------------------------------------------------
// Main: segment-aligned ownership. Wave w owns every segment s whose START
// B[s] lies in [w*CHUNK, (w+1)*CHUNK) (last wave: inclusive upper bound to
// catch trailing empties with start == n_atoms). Each owned segment is
// processed IN FULL (reads may overhang the window) and its mean stored
// directly — no atomics, no pre-zeroing, single output write per row.
// s0 is found by a uniform binary search over B (64 KB, L2-hot, broadcast).
// Lane layout: a_sub in {0,1} = which of 2 concurrent atoms, g in [0,32) =
// which float4. 4-deep pipeline (4 KB/wave-iter in flight).
// ---------------------------------------------------------------------------
__global__ void segmean_aligned_kernel(
    const float* __restrict__ atom_fea,
    const int*   __restrict__ B,
    float*       __restrict__ out,
    int n_atoms, int n_seg, int n_chunks)
{
    const int wid  = (blockIdx.x * 256 + threadIdx.x) >> 6;
    if (wid >= n_chunks) return;
    const int lane = threadIdx.x & 63;

    const int  c0   = wid * CHUNK;
    const int  c1   = min(c0 + CHUNK, n_atoms);
    const bool last = (wid == n_chunks - 1);

    // s0 = lower_bound(B, c0) over s in [0, n_seg]   (uniform -> broadcast)
    int lo = 0, hi = n_seg + 1;
    while (lo < hi) {
        const int mid = (lo + hi) >> 1;
        if (B[mid] < c0) lo = mid + 1; else hi = mid;
    }

    const int a_sub = lane >> 5;
    const int g     = lane & 31;

    for (int s = lo; s < n_seg; ++s) {
        const int segS = B[s];
        if (last ? (segS > c1) : (segS >= c1)) break;   // start outside window
        const int segE = B[s + 1];
        const int n    = segE - segS;

        const f4* base = (const f4*)atom_fea + (size_t)segS * (FEA / 4) + g;

        f4 a0 = {0.f, 0.f, 0.f, 0.f};
        f4 a1 = {0.f, 0.f, 0.f, 0.f};
        f4 a2 = {0.f, 0.f, 0.f, 0.f};
        f4 a3 = {0.f, 0.f, 0.f, 0.f};

        int k = a_sub;
        for (; k + 6 < n; k += 8) {          // 4 loads (4 KB/wave-iter) in flight
            f4 v0 = base[(size_t)(k    ) * 32];
            f4 v1 = base[(size_t)(k + 2) * 32];
            f4 v2 = base[(size_t)(k + 4) * 32];
            f4 v3 = base[(size_t)(k + 6) * 32];
            a0 += v0; a1 += v1; a2 += v2; a3 += v3;
        }
        for (; k < n; k += 2)
            a0 += base[(size_t)k * 32];

        a0 += a1 + a2 + a3;

        a0[0] += __shfl_xor(a0[0], 32, 64);
        a0[1] += __shfl_xor(a0[1], 32, 64);
        a0[2] += __shfl_xor(a0[2], 32, 64);
        a0[3] += __shfl_xor(a0[3], 32, 64);

        const float invn = 1.0f / (float)((n > 0) ? n : 1);  // empty -> writes 0

        if (a_sub == 0) {
            f4 r = a0 * invn;
            ((f4*)(out + (size_t)s * FEA))[g] = r;
        }
    }
}

// ---------------------------------------------------------------------------
// Fallback (ws too small): self-contained binary-search wave-per-segment.
// ---------------------------------------------------------------------------
__global__ __launch_bounds__(256) void segmean_bsearch_kernel(
    const float* __restrict__ atom_fea,
    const int*   __restrict__ ids,
    float*       __restrict__ out,
    int n_atoms, int n_seg)
{
    const int wave = threadIdx.x >> 6;
    const int lane = threadIdx.x & 63;
    const int seg  = blockIdx.x * 4 + wave;
    if (seg >= n_seg) return;

    int lo0 = 0, hi0 = n_atoms, lo1 = 0, hi1 = n_atoms;
    while ((lo0 < hi0) | (lo1 < hi1)) {
        if (lo0 < hi0) { int m = (lo0 + hi0) >> 1; if (ids[m] < seg)     lo0 = m + 1; else hi0 = m; }
        if (lo1 < hi1) { int m = (lo1 + hi1) >> 1; if (ids[m] < seg + 1) lo1 = m + 1; else hi1 = m; }
    }
    const int start = lo0;
    const int n     = lo1 - lo0;

    const int a_sub = lane >> 5;
    const int g     = lane & 31;
    const f4* base  = (const f4*)atom_fea + (size_t)start * (FEA / 4) + g;

    f4 a0 = {0.f, 0.f, 0.f, 0.f};
    for (int k = a_sub; k < n; k += 2)
        a0 += base[(size_t)k * 32];

    a0[0] += __shfl_xor(a0[0], 32, 64);
    a0[1] += __shfl_xor(a0[1], 32, 64);
    a0[2] += __shfl_xor(a0[2], 32, 64);
    a0[3] += __shfl_xor(a0[3], 32, 64);

    const float invn = 1.0f / (float)((n > 0) ? n : 1);
    if (a_sub == 0) {
        f4 r = a0 * invn;
        ((f4*)(out + (size_t)seg * FEA))[g] = r;
    }
}

extern "C" void kernel_launch(void* const* d_in, const int* in_sizes, int n_in,
                              void* d_out, int out_size, void* d_ws, size_t ws_size,
                              hipStream_t stream) {
    const float* atom_fea = (const float*)d_in[0];
    const int*   ids      = (const int*)d_in[1];
    float*       out      = (float*)d_out;

    const int n_atoms = in_sizes[1];
    const int n_seg   = out_size / FEA;

    const size_t bounds_bytes = (size_t)(n_seg + 1) * sizeof(int);
    const int    n_chunks     = (n_atoms + CHUNK - 1) / CHUNK;

    if (ws_size >= bounds_bytes) {
        int* B = (int*)d_ws;

        const int b_blocks = (((n_atoms + 3) / 4) + 255) / 256;
        bounds_kernel<<<b_blocks, 256, 0, stream>>>(ids, B, n_atoms, n_seg);

        const int m_blocks = (n_chunks + 3) / 4;   // 4 waves (windows) per block
        segmean_aligned_kernel<<<m_blocks, 256, 0, stream>>>(
            atom_fea, B, out, n_atoms, n_seg, n_chunks);
    } else {
        const int seg_blocks = (n_seg + 3) / 4;
        segmean_bsearch_kernel<<<seg_blocks, 256, 0, stream>>>(
            atom_fea, ids, out, n_atoms, n_seg);
    }
}

// Round 8
// 108.786 us; speedup vs baseline: 4.5457x; 1.0834x over previous
//
#include <hip/hip_runtime.h>

#define FEA   128   // floats per atom row (512 B)
#define CHUNK 128   // atoms per wave (64 KB contiguous stream per wave)

typedef float f4 __attribute__((ext_vector_type(4)));

// ---------------------------------------------------------------------------
// Prologue (one launch, two thread roles by blockIdx):
//  role A: build B[s] = lower_bound(ids, s) for s in [0, n_seg]; zero rows of
//          empty segments (B[s]==B[s+1]).
//  role B: for each chunk boundary p = k*CHUNK, if ids[p-1]==ids[p] the
//          segment straddles the boundary -> zero its output row (it will be
//          accumulated via atomicAdd by the main kernel).
// ---------------------------------------------------------------------------
__global__ __launch_bounds__(256) void prologue_kernel(
    const int* __restrict__ ids, int* __restrict__ B, float* __restrict__ out,
    int n_atoms, int n_seg, int b_blocks, int n_chunks)
{
    if ((int)blockIdx.x < b_blocks) {
        // ---- role A: bounds + empty rows ----
        const int t  = blockIdx.x * 256 + threadIdx.x;
        const int i0 = t * 4;
        if (i0 >= n_atoms) return;
        int prev = (i0 == 0) ? -1 : ids[i0 - 1];
        #pragma unroll
        for (int j = 0; j < 4; ++j) {
            const int i = i0 + j;
            if (i >= n_atoms) break;
            const int cur = ids[i];
            if (cur != prev) {
                for (int s = prev + 1; s <= cur; ++s) B[s] = i;
                for (int s = prev + 1; s < cur; ++s) {        // empty segments
                    f4* row = (f4*)(out + (size_t)s * FEA);
                    const f4 z = {0.f, 0.f, 0.f, 0.f};
                    for (int q = 0; q < FEA / 4; ++q) row[q] = z;
                }
                prev = cur;
            }
        }
        if (i0 + 4 >= n_atoms) {
            for (int s = prev + 1; s <= n_seg; ++s) B[s] = n_atoms;
            for (int s = prev + 1; s < n_seg; ++s) {          // trailing empties
                f4* row = (f4*)(out + (size_t)s * FEA);
                const f4 z = {0.f, 0.f, 0.f, 0.f};
                for (int q = 0; q < FEA / 4; ++q) row[q] = z;
            }
        }
    } else {
        // ---- role B: zero straddler rows (32 lanes per boundary, coalesced) ----
        const int t = ((int)blockIdx.x - b_blocks) * 256 + threadIdx.x;
        const int b = t >> 5;          // boundary index
        const int g = t & 31;
        const int p = (b + 1) * CHUNK;
        if (b >= n_chunks - 1 || p >= n_atoms) return;
        const int sl = ids[p - 1];
        const int sr = ids[p];
        if (sl == sr) {
            const f4 z = {0.f, 0.f, 0.f, 0.f};
            ((f4*)(out + (size_t)sr * FEA))[g] = z;
        }
    }
}

// ---------------------------------------------------------------------------
// Main: one wave per fixed 128-atom chunk (perfectly balanced; 8192 waves =
// exactly one full residency round at 32 waves/CU). Walk the segments
// overlapping the chunk using B[]; interior segments -> direct mean write;
// straddlers -> pre-divided atomicAdd. Lane layout: a_sub in {0,1} picks
// which of 2 concurrent atoms, g in [0,32) picks the float4 (1 KB per
// wave-instruction). 4-deep load pipeline (4 KB/wave-iter in flight).
// ---------------------------------------------------------------------------
__global__ void segmean_chunk_kernel(
    const float* __restrict__ atom_fea,
    const int*   __restrict__ ids,
    const int*   __restrict__ B,
    float*       __restrict__ out,
    int n_atoms)
{
    const int wid   = (blockIdx.x * 256 + threadIdx.x) >> 6;
    const int lane  = threadIdx.x & 63;
    const int c0    = wid * CHUNK;
    if (c0 >= n_atoms) return;
    const int c1    = min(c0 + CHUNK, n_atoms);
    const int a_sub = lane >> 5;
    const int g     = lane & 31;

    int s   = ids[c0];    // segment containing the chunk's first atom
    int pos = c0;

    while (pos < c1) {
        const int segS = B[s];
        const int segE = B[s + 1];
        const int e    = min(segE, c1);
        const int m    = e - pos;            // atoms of segment s in this chunk

        const f4* base = (const f4*)atom_fea + (size_t)pos * (FEA / 4) + g;

        f4 a0 = {0.f, 0.f, 0.f, 0.f};
        f4 a1 = {0.f, 0.f, 0.f, 0.f};
        f4 a2 = {0.f, 0.f, 0.f, 0.f};
        f4 a3 = {0.f, 0.f, 0.f, 0.f};

        int k = a_sub;
        for (; k + 6 < m; k += 8) {          // 4 nt loads in flight (4 KB/wave-iter)
            f4 v0 = __builtin_nontemporal_load(base + (size_t)k       * 32);
            f4 v1 = __builtin_nontemporal_load(base + (size_t)(k + 2) * 32);
            f4 v2 = __builtin_nontemporal_load(base + (size_t)(k + 4) * 32);
            f4 v3 = __builtin_nontemporal_load(base + (size_t)(k + 6) * 32);
            a0 += v0; a1 += v1; a2 += v2; a3 += v3;
        }
        for (; k < m; k += 2)
            a0 += __builtin_nontemporal_load(base + (size_t)k * 32);

        a0 += a1 + a2 + a3;

        a0[0] += __shfl_xor(a0[0], 32, 64);
        a0[1] += __shfl_xor(a0[1], 32, 64);
        a0[2] += __shfl_xor(a0[2], 32, 64);
        a0[3] += __shfl_xor(a0[3], 32, 64);

        const int   n_total = segE - segS;
        const float invn    = 1.0f / (float)((n_total > 0) ? n_total : 1);

        if (segS >= c0 && segE <= c1) {
            // interior (or empty) segment: exclusive owner -> direct write
            if (a_sub == 0) {
                f4 r = a0 * invn;
                ((f4*)(out + (size_t)s * FEA))[g] = r;
            }
        } else {
            // straddler: row was zeroed in prologue -> pre-divided atomic add
            if (a_sub == 0) {
                float* dst = out + (size_t)s * FEA + g * 4;
                atomicAdd(dst + 0, a0[0] * invn);
                atomicAdd(dst + 1, a0[1] * invn);
                atomicAdd(dst + 2, a0[2] * invn);
                atomicAdd(dst + 3, a0[3] * invn);
            }
        }
        pos = e;
        ++s;
    }
}

// ---------------------------------------------------------------------------
// Fallback (ws too small): binary-search wave-per-segment variant.
// ---------------------------------------------------------------------------
__global__ __launch_bounds__(256) void segmean_bsearch_kernel(
    const float* __restrict__ atom_fea,
    const int*   __restrict__ ids,
    float*       __restrict__ out,
    int n_atoms, int n_seg)
{
    const int wave = threadIdx.x >> 6;
    const int lane = threadIdx.x & 63;
    const int seg  = blockIdx.x * 4 + wave;
    if (seg >= n_seg) return;

    int lo0 = 0, hi0 = n_atoms, lo1 = 0, hi1 = n_atoms;
    while ((lo0 < hi0) | (lo1 < hi1)) {
        if (lo0 < hi0) { int m = (lo0 + hi0) >> 1; if (ids[m] < seg)     lo0 = m + 1; else hi0 = m; }
        if (lo1 < hi1) { int m = (lo1 + hi1) >> 1; if (ids[m] < seg + 1) lo1 = m + 1; else hi1 = m; }
    }
    const int start = lo0;
    const int n     = lo1 - lo0;

    const int a_sub = lane >> 5;
    const int g     = lane & 31;
    const f4* base  = (const f4*)atom_fea + (size_t)start * (FEA / 4) + g;

    f4 a0 = {0.f, 0.f, 0.f, 0.f};
    for (int k = a_sub; k < n; k += 2)
        a0 += *(base + (size_t)k * 32);

    a0[0] += __shfl_xor(a0[0], 32, 64);
    a0[1] += __shfl_xor(a0[1], 32, 64);
    a0[2] += __shfl_xor(a0[2], 32, 64);
    a0[3] += __shfl_xor(a0[3], 32, 64);

    const float invn = 1.0f / (float)((n > 0) ? n : 1);
    if (a_sub == 0) {
        f4 r = a0 * invn;
        ((f4*)(out + (size_t)seg * FEA))[g] = r;
    }
}

extern "C" void kernel_launch(void* const* d_in, const int* in_sizes, int n_in,
                              void* d_out, int out_size, void* d_ws, size_t ws_size,
                              hipStream_t stream) {
    const float* atom_fea = (const float*)d_in[0];
    const int*   ids      = (const int*)d_in[1];
    float*       out      = (float*)d_out;

    const int n_atoms = in_sizes[1];
    const int n_seg   = out_size / FEA;

    const size_t bounds_bytes = (size_t)(n_seg + 1) * sizeof(int);

    if (ws_size >= bounds_bytes) {
        int* B = (int*)d_ws;

        const int n_chunks = (n_atoms + CHUNK - 1) / CHUNK;
        const int b_blocks = (((n_atoms + 3) / 4) + 255) / 256;
        const int z_thr    = (n_chunks > 1) ? (n_chunks - 1) * 32 : 0;
        const int z_blocks = (z_thr + 255) / 256;

        prologue_kernel<<<b_blocks + z_blocks, 256, 0, stream>>>(
            ids, B, out, n_atoms, n_seg, b_blocks, n_chunks);

        const int m_blocks = (n_chunks + 3) / 4;   // 4 waves (chunks) per block
        segmean_chunk_kernel<<<m_blocks, 256, 0, stream>>>(
            atom_fea, ids, B, out, n_atoms);
    } else {
        const int seg_blocks = (n_seg + 3) / 4;
        segmean_bsearch_kernel<<<seg_blocks, 256, 0, stream>>>(
            atom_fea, ids, out, n_atoms, n_seg);
    }
}